// Round 4
// baseline (458.579 us; speedup 1.0000x reference)
//
#include <hip/hip_runtime.h>

typedef unsigned int u32;
typedef unsigned long long u64;

#define R_ROUNDS 64
#define HID 256
#define BATCH 16384
#define RPW 4   // batch rows per wave

// ---------------------------------------------------------------------------
// GF(2) reduction of the reference:
//   s' = (floor(s@M^T + n)) mod 2, s,n in {0,1}, M in {-1,0,1}
//      = parity(popcount(s & (M!=0) row)) XOR n        (-1 == 1 mod 2)
//
// pi-order packing: lane l owns bits {4l..4l+3}; packed u64 word k has
// bit l = vector bit (4l+k). All float traffic is dwordx4-coalesced.
//
// Round 4 structure: raw s_barrier (1/round, NO vmcnt(0) drain), quad-
// buffered LDS masks staged 2 rounds ahead via global_load_lds, noise
// double-buffered in registers 1 round ahead. Cross-wave stage handoff
// relies on in-order vmcnt retirement: noise(r) is issued after stage(r+1)
// in program order, so the compiler's own wait for noise(r) registers
// (before RUN(r)) drains stage(r+1); barrier B_{r+1} then publishes it.
// ---------------------------------------------------------------------------

// Pack ternary matrices -> pi-ordered bitmasks. One wave per (r,j) row.
// P[row*8 + 2i+h] = half h of u64 W_i, where W_i bit l = (M[row][4l+i]!=0).
__global__ __launch_bounds__(256) void pack_matrices_kernel(
        const float* __restrict__ M, u32* __restrict__ P) {
    const int lane = threadIdx.x & 63;
    const int row  = (int)((blockIdx.x * blockDim.x + threadIdx.x) >> 6);
    const float4 v = *(const float4*)(M + (size_t)row * HID + 4 * lane);
    const u64 b0 = __ballot(v.x != 0.0f);
    const u64 b1 = __ballot(v.y != 0.0f);
    const u64 b2 = __ballot(v.z != 0.0f);
    const u64 b3 = __ballot(v.w != 0.0f);
    if (lane < 8) {
        const int i = lane >> 1;
        u64 bb = b0;
        if (i == 1) bb = b1;
        if (i == 2) bb = b2;
        if (i == 3) bb = b3;
        P[row * 8 + lane] = (lane & 1) ? (u32)(bb >> 32) : (u32)bb;
    }
}

__global__ __launch_bounds__(256, 4) void tenshash_kernel(
        const float* __restrict__ state,
        const u32*  __restrict__ pA,
        const float* __restrict__ noise,
        float* __restrict__ out) {
    const int lane = threadIdx.x & 63;
    const int warp = threadIdx.x >> 6;
    const int wave = (int)(blockIdx.x * 4 + warp);
    const int row0 = wave * RPW;

    __shared__ u32 smem[4][2048];   // 4 x 8KB mask buffers (reuse distance 4)

    // ---- init state (pi-order): S_k[rw] bit l = state bit (4l+k) ----
    u64 S0[RPW], S1[RPW], S2[RPW], S3[RPW];
#pragma unroll
    for (int rw = 0; rw < RPW; ++rw) {
        const float4 v = *(const float4*)(state + (size_t)(row0 + rw) * HID + 4 * lane);
        S0[rw] = __ballot(v.x != 0.0f);
        S1[rw] = __ballot(v.y != 0.0f);
        S2[rw] = __ballot(v.z != 0.0f);
        S3[rw] = __ballot(v.w != 0.0f);
    }

    const float* no_l = noise + (size_t)row0 * (R_ROUNDS * HID) + 4 * lane;

    // Source-side swizzle: LDS 16B-slot u' = 64*t + lane holds global chunk
    // 64t + 8a + (b^a), a=lane>>3, b=lane&7 (inverse of the read swizzle).
    const int sa = lane >> 3, sb = lane & 7;
    const int src_chunk_lo = (sa << 3) + (sb ^ sa);
    // Each wave stages 2 of the 8 1KB-chunks (symmetric outstanding counts).
    auto STAGE = [&](int r, int b) {
        const char* g = (const char*)(pA + (size_t)r * 2048);
#pragma unroll
        for (int t = 2 * warp; t < 2 * warp + 2; ++t) {
            __builtin_amdgcn_global_load_lds(
                (const __attribute__((address_space(1))) void*)
                    (g + t * 1024 + src_chunk_lo * 16),
                (__attribute__((address_space(3))) void*)&smem[b][t * 256],
                16, 0, 0);
        }
    };
    auto LOADN = [&](float4* n, int r) {
#pragma unroll
        for (int rw = 0; rw < RPW; ++rw)
            n[rw] = *(const float4*)(no_l + (size_t)rw * (R_ROUNDS * HID) + r * HID);
    };
    // Swizzled LDS read: chunk (8*lane + t) lives at slot 8*lane + (t^(lane&7)).
    auto RUN = [&](const u32* sb_, const float4* n) {
        const uint4* p = (const uint4*)sb_;
        uint4 a[8];
#pragma unroll
        for (int t = 0; t < 8; ++t)
            a[t] = p[(lane << 3) + (t ^ (lane & 7))];
#pragma unroll
        for (int rw = 0; rw < RPW; ++rw) {
            u64 ns0, ns1, ns2, ns3;
#pragma unroll
            for (int i = 0; i < 4; ++i) {
                const u64 W0 = (u64)a[2 * i].x     | ((u64)a[2 * i].y     << 32);
                const u64 W1 = (u64)a[2 * i].z     | ((u64)a[2 * i].w     << 32);
                const u64 W2 = (u64)a[2 * i + 1].x | ((u64)a[2 * i + 1].y << 32);
                const u64 W3 = (u64)a[2 * i + 1].z | ((u64)a[2 * i + 1].w << 32);
                const float nfv = (i == 0) ? n[rw].x : (i == 1) ? n[rw].y
                                : (i == 2) ? n[rw].z : n[rw].w;
                const u32 c = (u32)__popcll(W0 & S0[rw]) + (u32)__popcll(W1 & S1[rw])
                            + (u32)__popcll(W2 & S2[rw]) + (u32)__popcll(W3 & S3[rw])
                            + (u32)nfv;                    // exact: nfv in {0.0,1.0}
                const u64 nb = __ballot((c & 1u) != 0);
                if (i == 0) ns0 = nb; else if (i == 1) ns1 = nb;
                else if (i == 2) ns2 = nb; else ns3 = nb;
            }
            S0[rw] = ns0; S1[rw] = ns1; S2[rw] = ns2; S3[rw] = ns3;
        }
    };

    float4 nA[RPW], nB[RPW];

    // ---- prologue: buffers 0,1 staged + noise(0); publish before B_0 ----
    STAGE(0, 0);
    STAGE(1, 1);
    __builtin_amdgcn_sched_barrier(0);
    asm volatile("" ::: "memory");
    LOADN(nA, 0);
    asm volatile("s_waitcnt vmcnt(4)" ::: "memory");  // drain stages, keep noise(0)
    __builtin_amdgcn_sched_barrier(0);

    // sub-round k (r%4==0): barrier; stage r+k+2 -> buf (k+2)&3;
    // load noise r+k+1; compute round r+k from buf k.
#define SUBROUND(k, BUFS, NUSE, NLOAD)                                   \
    asm volatile("" ::: "memory");                                       \
    __builtin_amdgcn_s_barrier();                                        \
    asm volatile("" ::: "memory");                                       \
    if (r + k + 2 < R_ROUNDS) STAGE(r + k + 2, BUFS);                    \
    __builtin_amdgcn_sched_barrier(0);                                   \
    asm volatile("" ::: "memory");                                       \
    { int rn = r + k + 1; if (rn > R_ROUNDS - 1) rn = R_ROUNDS - 1;      \
      LOADN(NLOAD, rn); }                                                \
    RUN(&smem[k][0], NUSE);

#pragma unroll 1
    for (int r = 0; r < R_ROUNDS; r += 4) {
        SUBROUND(0, 2, nA, nB)
        SUBROUND(1, 3, nB, nA)
        SUBROUND(2, 0, nA, nB)
        SUBROUND(3, 1, nB, nA)
    }
#undef SUBROUND

    // ---- unpack final state, float4 stores ----
#pragma unroll
    for (int rw = 0; rw < RPW; ++rw) {
        float4 o;
        o.x = (float)((u32)(S0[rw] >> lane) & 1u);
        o.y = (float)((u32)(S1[rw] >> lane) & 1u);
        o.z = (float)((u32)(S2[rw] >> lane) & 1u);
        o.w = (float)((u32)(S3[rw] >> lane) & 1u);
        *(float4*)(out + (size_t)(row0 + rw) * HID + 4 * lane) = o;
    }
}

extern "C" void kernel_launch(void* const* d_in, const int* in_sizes, int n_in,
                              void* d_out, int out_size, void* d_ws, size_t ws_size,
                              hipStream_t stream) {
    const float* state = (const float*)d_in[0];
    const float* mats  = (const float*)d_in[1];
    const float* noise = (const float*)d_in[2];
    float* out         = (float*)d_out;
    u32* pA            = (u32*)d_ws;              // 512 KB packed masks

    pack_matrices_kernel<<<(R_ROUNDS * HID) / 4, 256, 0, stream>>>(mats, pA);

    const int blocks = (BATCH / RPW) / 4;         // 1024 blocks x 4 waves
    tenshash_kernel<<<blocks, 256, 0, stream>>>(state, pA, noise, out);
}

// Round 5
// 248.674 us; speedup vs baseline: 1.8441x; 1.8441x over previous
//
#include <hip/hip_runtime.h>

typedef unsigned int u32;
typedef unsigned long long u64;

#define R_ROUNDS 64
#define HID 256
#define BATCH 16384
#define RPW 4   // batch rows per wave

// ---------------------------------------------------------------------------
// GF(2) reduction of the reference:
//   s' = (floor(s@M^T + n)) mod 2, s,n in {0,1}, M in {-1,0,1}
//      = parity(popcount(s & (M!=0) row)) XOR n        (-1 == 1 mod 2)
//
// pi-order packing: lane l owns bits {4l..4l+3}; packed u64 word k has
// bit l = vector bit (4l+k). All float traffic is dwordx4-coalesced.
//
// Round 5 structure (round-3 + wider phases, NO inline-asm scheduling):
// 2 rounds per barrier phase. Per phase: issue 2 rounds of noise (HBM)
// and stage 16KB of masks (L2) at the top, then compute 2 RUNs (~1280cyc)
// before the __syncthreads. Every load the barrier's implicit vmcnt(0)
// drains has been in flight >= 1280 cyc >= HBM latency -> ~zero drain
// stall, and only 32 barriers total.
// ---------------------------------------------------------------------------

// Pack ternary matrices -> pi-ordered bitmasks. One wave per (r,j) row.
// P[row*8 + 2i+h] = half h of u64 W_i, where W_i bit l = (M[row][4l+i]!=0).
__global__ __launch_bounds__(256) void pack_matrices_kernel(
        const float* __restrict__ M, u32* __restrict__ P) {
    const int lane = threadIdx.x & 63;
    const int row  = (int)((blockIdx.x * blockDim.x + threadIdx.x) >> 6);
    const float4 v = *(const float4*)(M + (size_t)row * HID + 4 * lane);
    const u64 b0 = __ballot(v.x != 0.0f);
    const u64 b1 = __ballot(v.y != 0.0f);
    const u64 b2 = __ballot(v.z != 0.0f);
    const u64 b3 = __ballot(v.w != 0.0f);
    if (lane < 8) {
        const int i = lane >> 1;
        u64 bb = b0;
        if (i == 1) bb = b1;
        if (i == 2) bb = b2;
        if (i == 3) bb = b3;
        P[row * 8 + lane] = (lane & 1) ? (u32)(bb >> 32) : (u32)bb;
    }
}

__global__ __launch_bounds__(256, 4) void tenshash_kernel(
        const float* __restrict__ state,
        const u32*  __restrict__ pA,
        const float* __restrict__ noise,
        float* __restrict__ out) {
    const int lane = threadIdx.x & 63;
    const int warp = threadIdx.x >> 6;
    const int wave = (int)(blockIdx.x * 4 + warp);
    const int row0 = wave * RPW;

    __shared__ u32 smem[2][4096];   // 2 x 16KB phase buffers (2 rounds each)

    // ---- init state (pi-order): S_k[rw] bit l = state bit (4l+k) ----
    u64 S0[RPW], S1[RPW], S2[RPW], S3[RPW];
#pragma unroll
    for (int rw = 0; rw < RPW; ++rw) {
        const float4 v = *(const float4*)(state + (size_t)(row0 + rw) * HID + 4 * lane);
        S0[rw] = __ballot(v.x != 0.0f);
        S1[rw] = __ballot(v.y != 0.0f);
        S2[rw] = __ballot(v.z != 0.0f);
        S3[rw] = __ballot(v.w != 0.0f);
    }

    const float* no_l = noise + (size_t)row0 * (R_ROUNDS * HID) + 4 * lane;

    // Source-side swizzle: LDS 16B-slot u' = 64*t + lane holds global chunk
    // 64t + 8a + (b^a), a=lane>>3, b=lane&7 (inverse of the read swizzle).
    const int sa = lane >> 3, sb = lane & 7;
    const int src_chunk_lo = (sa << 3) + (sb ^ sa);

    // Stage rounds (q, q+1) = 16KB into buffer b. 16 x 1KB chunks; each
    // wave stages chunks 4*warp .. 4*warp+3 (4 x global_load_lds of 16B/lane).
    auto STAGE = [&](int q, int b) {
        const char* g = (const char*)(pA + (size_t)q * 2048);
#pragma unroll
        for (int t = 4 * warp; t < 4 * warp + 4; ++t) {
            __builtin_amdgcn_global_load_lds(
                (const __attribute__((address_space(1))) void*)
                    (g + t * 1024 + src_chunk_lo * 16),
                (__attribute__((address_space(3))) void*)&smem[b][t * 256],
                16, 0, 0);
        }
    };
    auto LOADN = [&](float4* n, int r) {
#pragma unroll
        for (int rw = 0; rw < RPW; ++rw)
            n[rw] = *(const float4*)(no_l + (size_t)rw * (R_ROUNDS * HID) + r * HID);
    };
    // Swizzled LDS read: chunk (8*lane + t) of an 8KB round block lives at
    // 16B-slot 8*lane + (t ^ (lane&7))  -> 2-way bank aliasing only (free).
    auto RUN = [&](const u32* base, const float4* n) {
        const uint4* p = (const uint4*)base;
        uint4 a[8];
#pragma unroll
        for (int t = 0; t < 8; ++t)
            a[t] = p[(lane << 3) + (t ^ (lane & 7))];
#pragma unroll
        for (int rw = 0; rw < RPW; ++rw) {
            u64 ns0, ns1, ns2, ns3;
#pragma unroll
            for (int i = 0; i < 4; ++i) {
                const u64 W0 = (u64)a[2 * i].x     | ((u64)a[2 * i].y     << 32);
                const u64 W1 = (u64)a[2 * i].z     | ((u64)a[2 * i].w     << 32);
                const u64 W2 = (u64)a[2 * i + 1].x | ((u64)a[2 * i + 1].y << 32);
                const u64 W3 = (u64)a[2 * i + 1].z | ((u64)a[2 * i + 1].w << 32);
                const float nfv = (i == 0) ? n[rw].x : (i == 1) ? n[rw].y
                                : (i == 2) ? n[rw].z : n[rw].w;
                const u32 c = (u32)__popcll(W0 & S0[rw]) + (u32)__popcll(W1 & S1[rw])
                            + (u32)__popcll(W2 & S2[rw]) + (u32)__popcll(W3 & S3[rw])
                            + (u32)nfv;                    // exact: nfv in {0.0,1.0}
                const u64 nb = __ballot((c & 1u) != 0);
                if (i == 0) ns0 = nb; else if (i == 1) ns1 = nb;
                else if (i == 2) ns2 = nb; else ns3 = nb;
            }
            S0[rw] = ns0; S1[rw] = ns1; S2[rw] = ns2; S3[rw] = ns3;
        }
    };

    float4 n0[RPW], n1[RPW], n2[RPW], n3[RPW];

    // ---- prologue: noise rounds 0,1 + mask rounds 0,1 into buf0 ----
    LOADN(n0, 0);
    LOADN(n1, 1);
    STAGE(0, 0);
    __syncthreads();

#pragma unroll 1
    for (int r = 0; r < R_ROUNDS; r += 4) {
        // ---- phase A: compute rounds r, r+1 from buf0 ----
        LOADN(n2, r + 2);                 // r <= 60 so r+2,r+3 <= 63: no clamp
        LOADN(n3, r + 3);
        STAGE(r + 2, 1);                  // stage rounds r+2,r+3 (q <= 62)
        RUN(&smem[0][0],    n0);          // round r
        RUN(&smem[0][2048], n1);          // round r+1
        __syncthreads();                  // all drained loads >=1280cyc old

        // ---- phase B: compute rounds r+2, r+3 from buf1 ----
        {
            const int ra = (r + 4 > 63) ? 63 : r + 4;   // clamped redundant
            const int rb = (r + 5 > 63) ? 63 : r + 5;   // loads on last iter
            LOADN(n0, ra);
            LOADN(n1, rb);
        }
        {
            const int q = (r + 4 > 62) ? 62 : r + 4;    // clamped restage into
            STAGE(q, 0);                                // buf0 (unread at end)
        }
        RUN(&smem[1][0],    n2);          // round r+2
        RUN(&smem[1][2048], n3);          // round r+3
        __syncthreads();
    }

    // ---- unpack final state, float4 stores ----
#pragma unroll
    for (int rw = 0; rw < RPW; ++rw) {
        float4 o;
        o.x = (float)((u32)(S0[rw] >> lane) & 1u);
        o.y = (float)((u32)(S1[rw] >> lane) & 1u);
        o.z = (float)((u32)(S2[rw] >> lane) & 1u);
        o.w = (float)((u32)(S3[rw] >> lane) & 1u);
        *(float4*)(out + (size_t)(row0 + rw) * HID + 4 * lane) = o;
    }
}

extern "C" void kernel_launch(void* const* d_in, const int* in_sizes, int n_in,
                              void* d_out, int out_size, void* d_ws, size_t ws_size,
                              hipStream_t stream) {
    const float* state = (const float*)d_in[0];
    const float* mats  = (const float*)d_in[1];
    const float* noise = (const float*)d_in[2];
    float* out         = (float*)d_out;
    u32* pA            = (u32*)d_ws;              // 512 KB packed masks

    pack_matrices_kernel<<<(R_ROUNDS * HID) / 4, 256, 0, stream>>>(mats, pA);

    const int blocks = (BATCH / RPW) / 4;         // 1024 blocks x 4 waves
    tenshash_kernel<<<blocks, 256, 0, stream>>>(state, pA, noise, out);
}